// Round 1
// baseline (2019.012 us; speedup 1.0000x reference)
//
#include <hip/hip_runtime.h>

namespace {

constexpr int TT = 512;   // timesteps
constexpr int H  = 64;    // hidden
constexpr int G4 = 4 * H; // 256 gate rows
constexpr int NB = 4;     // batch elements per block
constexpr int NT = 256;   // threads per block

__device__ __forceinline__ float sigm(float z) {
    // 1/(1+e^-z); rcp approx ~1ulp, fine vs 3.8e-4 threshold
    return __builtin_amdgcn_rcpf(1.0f + __expf(-z));
}
__device__ __forceinline__ float tanh_fast(float z) {
    // tanh(z) = 2*sigmoid(2z) - 1
    return fmaf(2.0f, sigm(2.0f * z), -1.0f);
}

__global__ __launch_bounds__(NT, 2) void lstm2_kernel(
    const float* __restrict__ x,
    const float* __restrict__ W_ih0, const float* __restrict__ W_hh0,
    const float* __restrict__ b_ih0, const float* __restrict__ b_hh0,
    const float* __restrict__ W_ih1, const float* __restrict__ W_hh1,
    const float* __restrict__ b_ih1, const float* __restrict__ b_hh1,
    const float* __restrict__ fc_W,  const float* __restrict__ fc_b,
    float* __restrict__ out)
{
    __shared__ float  x_lds[NB * TT];   // 8 KB: this block's 4 input rows
    __shared__ float4 h1_lds[H];        // h1[k] for 4 batches (x,y,z,w)
    __shared__ float4 h2_lds[H];
    __shared__ float  g_lds[NB][G4];    // 4 KB gate exchange

    const int tid = threadIdx.x;
    const int b0  = blockIdx.x * NB;

    // stage this block's x rows (4 consecutive rows = contiguous) coalesced
    {
        const float4* src = (const float4*)(x + (size_t)b0 * TT);
        float4* dst = (float4*)x_lds;
        #pragma unroll
        for (int i = 0; i < NB * TT / 4 / NT; ++i)   // = 2
            dst[i * NT + tid] = src[i * NT + tid];
    }

    // Per-thread loop-invariant weights: thread t owns gate-row t of each matrix.
    // Fully unrolled constant-index arrays -> VGPRs (192 regs of weights).
    float w0[H];        // W_hh0 row
    float w1[2 * H];    // [W_ih1 row | W_hh1 row]
    #pragma unroll
    for (int k = 0; k < H; ++k) w0[k]     = W_hh0[tid * H + k];
    #pragma unroll
    for (int k = 0; k < H; ++k) w1[k]     = W_ih1[tid * H + k];
    #pragma unroll
    for (int k = 0; k < H; ++k) w1[H + k] = W_hh1[tid * H + k];
    const float wx  = W_ih0[tid];               // input dim is 1
    const float bs0 = b_ih0[tid] + b_hh0[tid];
    const float bs1 = b_ih1[tid] + b_hh1[tid];

    if (tid < H) {
        h1_lds[tid] = make_float4(0.f, 0.f, 0.f, 0.f);
        h2_lds[tid] = make_float4(0.f, 0.f, 0.f, 0.f);
    }
    float c1 = 0.f, c2 = 0.f;          // state element (bu, ju) owned here
    const int bu   = tid >> 6;         // 256 threads <-> 4 batches x 64 hidden
    const int ju   = tid & 63;
    const int gate = tid >> 6;         // wave-uniform gate type (i,f,g,o)
    __syncthreads();

    for (int t = 0; t < TT; ++t) {
        // ---------- layer 0: gates = x*W_ih0 + b + W_hh0 @ h1 ----------
        float a0 = fmaf(wx, x_lds[0 * TT + t], bs0);
        float a1 = fmaf(wx, x_lds[1 * TT + t], bs0);
        float a2 = fmaf(wx, x_lds[2 * TT + t], bs0);
        float a3 = fmaf(wx, x_lds[3 * TT + t], bs0);
        #pragma unroll
        for (int k = 0; k < H; ++k) {
            const float4 h = h1_lds[k];     // uniform address -> broadcast
            const float  w = w0[k];
            a0 = fmaf(w, h.x, a0);
            a1 = fmaf(w, h.y, a1);
            a2 = fmaf(w, h.z, a2);
            a3 = fmaf(w, h.w, a3);
        }
        if (gate == 2) {                    // g-gate wave: tanh
            a0 = tanh_fast(a0); a1 = tanh_fast(a1);
            a2 = tanh_fast(a2); a3 = tanh_fast(a3);
        } else {                            // i,f,o waves: sigmoid
            a0 = sigm(a0); a1 = sigm(a1); a2 = sigm(a2); a3 = sigm(a3);
        }
        g_lds[0][tid] = a0; g_lds[1][tid] = a1;
        g_lds[2][tid] = a2; g_lds[3][tid] = a3;
        __syncthreads();
        {
            const float gi = g_lds[bu][ju];
            const float gf = g_lds[bu][H + ju];
            const float gg = g_lds[bu][2 * H + ju];
            const float go = g_lds[bu][3 * H + ju];
            c1 = fmaf(gf, c1, gi * gg);
            ((float*)&h1_lds[ju])[bu] = go * tanh_fast(c1);
        }
        __syncthreads();

        // ---------- layer 1: gates = W_ih1 @ h1 + b + W_hh1 @ h2 ----------
        float d0 = bs1, d1 = bs1, d2 = bs1, d3 = bs1;
        #pragma unroll
        for (int k = 0; k < H; ++k) {
            const float4 h = h1_lds[k];
            const float  w = w1[k];
            d0 = fmaf(w, h.x, d0);
            d1 = fmaf(w, h.y, d1);
            d2 = fmaf(w, h.z, d2);
            d3 = fmaf(w, h.w, d3);
        }
        #pragma unroll
        for (int k = 0; k < H; ++k) {
            const float4 h = h2_lds[k];
            const float  w = w1[H + k];
            d0 = fmaf(w, h.x, d0);
            d1 = fmaf(w, h.y, d1);
            d2 = fmaf(w, h.z, d2);
            d3 = fmaf(w, h.w, d3);
        }
        if (gate == 2) {
            d0 = tanh_fast(d0); d1 = tanh_fast(d1);
            d2 = tanh_fast(d2); d3 = tanh_fast(d3);
        } else {
            d0 = sigm(d0); d1 = sigm(d1); d2 = sigm(d2); d3 = sigm(d3);
        }
        g_lds[0][tid] = d0; g_lds[1][tid] = d1;
        g_lds[2][tid] = d2; g_lds[3][tid] = d3;
        __syncthreads();
        {
            const float gi = g_lds[bu][ju];
            const float gf = g_lds[bu][H + ju];
            const float gg = g_lds[bu][2 * H + ju];
            const float go = g_lds[bu][3 * H + ju];
            c2 = fmaf(gf, c2, gi * gg);
            ((float*)&h2_lds[ju])[bu] = go * tanh_fast(c2);
        }
        __syncthreads();
    }

    // ---------- final FC on last h2 ----------
    if (tid < NB) {
        float s = fc_b[0];
        #pragma unroll
        for (int k = 0; k < H; ++k)
            s += fc_W[k] * ((const float*)&h2_lds[k])[tid];
        out[b0 + tid] = s;
    }
}

} // namespace

extern "C" void kernel_launch(void* const* d_in, const int* in_sizes, int n_in,
                              void* d_out, int out_size, void* d_ws, size_t ws_size,
                              hipStream_t stream)
{
    const float* x     = (const float*)d_in[0];
    const float* W_ih0 = (const float*)d_in[1];
    const float* W_hh0 = (const float*)d_in[2];
    const float* b_ih0 = (const float*)d_in[3];
    const float* b_hh0 = (const float*)d_in[4];
    const float* W_ih1 = (const float*)d_in[5];
    const float* W_hh1 = (const float*)d_in[6];
    const float* b_ih1 = (const float*)d_in[7];
    const float* b_hh1 = (const float*)d_in[8];
    const float* fc_W  = (const float*)d_in[9];
    const float* fc_b  = (const float*)d_in[10];
    float* out = (float*)d_out;

    const int B = in_sizes[0] / TT;      // 2048
    dim3 grid(B / NB), block(NT);        // 512 blocks x 256 threads
    hipLaunchKernelGGL(lstm2_kernel, grid, block, 0, stream,
                       x, W_ih0, W_hh0, b_ih0, b_hh0,
                       W_ih1, W_hh1, b_ih1, b_hh1, fc_W, fc_b, out);
}

// Round 2
// 1878.232 us; speedup vs baseline: 1.0750x; 1.0750x over previous
//
#include <hip/hip_runtime.h>

namespace {

constexpr int TT = 512;   // timesteps
constexpr int H  = 64;    // hidden
constexpr int G4 = 4 * H; // 256 gate rows
constexpr int NB = 4;     // batch elements per block
constexpr int NT = 256;   // threads per block

__device__ __forceinline__ float sigm(float z) {
    return __builtin_amdgcn_rcpf(1.0f + __expf(-z));
}
__device__ __forceinline__ float tanh_fast(float z) {
    return fmaf(2.0f, sigm(2.0f * z), -1.0f);
}

__global__ __launch_bounds__(NT, 2) void lstm2_kernel(
    const float* __restrict__ x,
    const float* __restrict__ W_ih0, const float* __restrict__ W_hh0,
    const float* __restrict__ b_ih0, const float* __restrict__ b_hh0,
    const float* __restrict__ W_ih1, const float* __restrict__ W_hh1,
    const float* __restrict__ b_ih1, const float* __restrict__ b_hh1,
    const float* __restrict__ fc_W,  const float* __restrict__ fc_b,
    float* __restrict__ out)
{
    __shared__ float  x_lds[NB * TT];   // 8 KB: this block's 4 input rows
    __shared__ float4 h1_lds[H];        // h1[k] for 4 batches (x,y,z,w)
    __shared__ float4 h2_lds[H];
    __shared__ float  g_lds[NB][G4];    // 4 KB gate exchange

    const int tid = threadIdx.x;
    const int b0  = blockIdx.x * NB;

    // stage this block's x rows coalesced
    {
        const float4* src = (const float4*)(x + (size_t)b0 * TT);
        float4* dst = (float4*)x_lds;
        #pragma unroll
        for (int i = 0; i < NB * TT / 4 / NT; ++i)   // = 2
            dst[i * NT + tid] = src[i * NT + tid];
    }

    // Per-thread loop-invariant weights: thread t owns gate-row t of each matrix.
    float w0[H];        // W_hh0 row
    float w1[2 * H];    // [W_ih1 row | W_hh1 row]
    #pragma unroll
    for (int k = 0; k < H; ++k) w0[k]     = W_hh0[tid * H + k];
    #pragma unroll
    for (int k = 0; k < H; ++k) w1[k]     = W_ih1[tid * H + k];
    #pragma unroll
    for (int k = 0; k < H; ++k) w1[H + k] = W_hh1[tid * H + k];
    float wx  = W_ih0[tid];
    float bs0 = b_ih0[tid] + b_hh0[tid];
    float bs1 = b_ih1[tid] + b_hh1[tid];

    // Pin weights into VGPRs: value origin becomes the asm, so the register
    // allocator cannot rematerialize the global loads inside the t-loop.
    // (Round-1 evidence: VGPR_Count=112 < 192 weights => they were reloaded
    // every timestep; dur 2.3ms at 70% VALUBusy, ~2.5x ideal VALU work.)
    #pragma unroll
    for (int k = 0; k < H; ++k)     asm volatile("" : "+v"(w0[k]));
    #pragma unroll
    for (int k = 0; k < 2 * H; ++k) asm volatile("" : "+v"(w1[k]));
    asm volatile("" : "+v"(wx));
    asm volatile("" : "+v"(bs0));
    asm volatile("" : "+v"(bs1));

    if (tid < H) {
        h1_lds[tid] = make_float4(0.f, 0.f, 0.f, 0.f);
        h2_lds[tid] = make_float4(0.f, 0.f, 0.f, 0.f);
    }
    float c1 = 0.f, c2 = 0.f;
    const int bu   = tid >> 6;         // 256 threads <-> 4 batches x 64 hidden
    const int ju   = tid & 63;
    const int gate = tid >> 6;         // wave-uniform gate type (i,f,g,o)
    __syncthreads();

    for (int t = 0; t < TT; ++t) {
        // ---------- layer 0: gates = x*W_ih0 + b + W_hh0 @ h1 ----------
        float a0 = fmaf(wx, x_lds[0 * TT + t], bs0);
        float a1 = fmaf(wx, x_lds[1 * TT + t], bs0);
        float a2 = fmaf(wx, x_lds[2 * TT + t], bs0);
        float a3 = fmaf(wx, x_lds[3 * TT + t], bs0);
        #pragma unroll
        for (int k = 0; k < H; ++k) {
            const float4 h = h1_lds[k];     // uniform address -> broadcast
            const float  w = w0[k];
            a0 = fmaf(w, h.x, a0);
            a1 = fmaf(w, h.y, a1);
            a2 = fmaf(w, h.z, a2);
            a3 = fmaf(w, h.w, a3);
        }
        if (gate == 2) {                    // g-gate wave: tanh
            a0 = tanh_fast(a0); a1 = tanh_fast(a1);
            a2 = tanh_fast(a2); a3 = tanh_fast(a3);
        } else {                            // i,f,o waves: sigmoid
            a0 = sigm(a0); a1 = sigm(a1); a2 = sigm(a2); a3 = sigm(a3);
        }
        g_lds[0][tid] = a0; g_lds[1][tid] = a1;
        g_lds[2][tid] = a2; g_lds[3][tid] = a3;
        __syncthreads();
        {
            const float gi = g_lds[bu][ju];
            const float gf = g_lds[bu][H + ju];
            const float gg = g_lds[bu][2 * H + ju];
            const float go = g_lds[bu][3 * H + ju];
            c1 = fmaf(gf, c1, gi * gg);
            ((float*)&h1_lds[ju])[bu] = go * tanh_fast(c1);
        }
        __syncthreads();

        // ---------- layer 1: gates = W_ih1 @ h1 + b + W_hh1 @ h2 ----------
        float d0 = bs1, d1 = bs1, d2 = bs1, d3 = bs1;
        #pragma unroll
        for (int k = 0; k < H; ++k) {
            const float4 p = h1_lds[k];
            const float  u = w1[k];
            d0 = fmaf(u, p.x, d0);
            d1 = fmaf(u, p.y, d1);
            d2 = fmaf(u, p.z, d2);
            d3 = fmaf(u, p.w, d3);
            const float4 q = h2_lds[k];
            const float  v = w1[H + k];
            d0 = fmaf(v, q.x, d0);
            d1 = fmaf(v, q.y, d1);
            d2 = fmaf(v, q.z, d2);
            d3 = fmaf(v, q.w, d3);
        }
        if (gate == 2) {
            d0 = tanh_fast(d0); d1 = tanh_fast(d1);
            d2 = tanh_fast(d2); d3 = tanh_fast(d3);
        } else {
            d0 = sigm(d0); d1 = sigm(d1); d2 = sigm(d2); d3 = sigm(d3);
        }
        g_lds[0][tid] = d0; g_lds[1][tid] = d1;
        g_lds[2][tid] = d2; g_lds[3][tid] = d3;
        __syncthreads();
        {
            const float gi = g_lds[bu][ju];
            const float gf = g_lds[bu][H + ju];
            const float gg = g_lds[bu][2 * H + ju];
            const float go = g_lds[bu][3 * H + ju];
            c2 = fmaf(gf, c2, gi * gg);
            ((float*)&h2_lds[ju])[bu] = go * tanh_fast(c2);
        }
        __syncthreads();
    }

    // ---------- final FC on last h2 ----------
    if (tid < NB) {
        float s = fc_b[0];
        #pragma unroll
        for (int k = 0; k < H; ++k)
            s += fc_W[k] * ((const float*)&h2_lds[k])[tid];
        out[b0 + tid] = s;
    }
}

} // namespace

extern "C" void kernel_launch(void* const* d_in, const int* in_sizes, int n_in,
                              void* d_out, int out_size, void* d_ws, size_t ws_size,
                              hipStream_t stream)
{
    const float* x     = (const float*)d_in[0];
    const float* W_ih0 = (const float*)d_in[1];
    const float* W_hh0 = (const float*)d_in[2];
    const float* b_ih0 = (const float*)d_in[3];
    const float* b_hh0 = (const float*)d_in[4];
    const float* W_ih1 = (const float*)d_in[5];
    const float* W_hh1 = (const float*)d_in[6];
    const float* b_ih1 = (const float*)d_in[7];
    const float* b_hh1 = (const float*)d_in[8];
    const float* fc_W  = (const float*)d_in[9];
    const float* fc_b  = (const float*)d_in[10];
    float* out = (float*)d_out;

    const int B = in_sizes[0] / TT;      // 2048
    dim3 grid(B / NB), block(NT);        // 512 blocks x 256 threads
    hipLaunchKernelGGL(lstm2_kernel, grid, block, 0, stream,
                       x, W_ih0, W_hh0, b_ih0, b_hh0,
                       W_ih1, W_hh1, b_ih1, b_hh1, fc_W, fc_b, out);
}

// Round 3
// 614.485 us; speedup vs baseline: 3.2857x; 3.0566x over previous
//
#include <hip/hip_runtime.h>

namespace {

constexpr int TT = 512;   // timesteps
constexpr int H  = 64;    // hidden units per layer
constexpr int NB = 8;     // real batches per block (MFMA cols 8..15 = padding)
constexpr int NT = 512;   // 8 waves: 0-3 -> layer0, 4-7 -> layer1

typedef float  f32x4  __attribute__((ext_vector_type(4)));
typedef short  bf16x8 __attribute__((ext_vector_type(8)));

#define MFMA(A, B, C) (C) = __builtin_amdgcn_mfma_f32_16x16x32_bf16((A), (B), (C), 0, 0, 0)

__device__ __forceinline__ float sigm(float z) {
    return __builtin_amdgcn_rcpf(1.0f + __expf(-z));
}
__device__ __forceinline__ float tanh_fast(float z) {
    return fmaf(2.0f, sigm(2.0f * z), -1.0f);
}
__device__ __forceinline__ unsigned short f2bf(float f) {
    unsigned u = __float_as_uint(f);
    return (unsigned short)((u + 0x7fffu + ((u >> 16) & 1u)) >> 16);
}
__device__ __forceinline__ float bf2f(unsigned short s) {
    return __uint_as_float(((unsigned)s) << 16);
}
// Load 8 consecutive floats, split into hi/lo bf16 fragments.
__device__ __forceinline__ void split8(const float* __restrict__ p, bf16x8& hi, bf16x8& lo) {
    float4 a = *(const float4*)p;
    float4 b = *(const float4*)(p + 4);
    float t[8] = {a.x, a.y, a.z, a.w, b.x, b.y, b.z, b.w};
    #pragma unroll
    for (int i = 0; i < 8; ++i) {
        unsigned short h = f2bf(t[i]);
        hi[i] = (short)h;
        lo[i] = (short)f2bf(t[i] - bf2f(h));
    }
}

__global__ __launch_bounds__(NT) void lstm2_mfma_kernel(
    const float* __restrict__ x,
    const float* __restrict__ W_ih0, const float* __restrict__ W_hh0,
    const float* __restrict__ b_ih0, const float* __restrict__ b_hh0,
    const float* __restrict__ W_ih1, const float* __restrict__ W_hh1,
    const float* __restrict__ b_ih1, const float* __restrict__ b_hh1,
    const float* __restrict__ fc_W,  const float* __restrict__ fc_b,
    float* __restrict__ out)
{
    // h fragments in B-operand order: [layer][dbuf][hi/lo][1024 bf16]
    __shared__ alignas(16) unsigned short hbuf[2][2][2][1024];   // 16 KB
    __shared__ float x_lds2[TT][NB];                             // 16 KB, [t][b]
    __shared__ float fc_part[16][NB];

    const int tid  = threadIdx.x;
    const int lane = tid & 63;
    const int wid  = tid >> 6;          // 0..7
    const int wloc = wid & 3;           // wave within its group
    const bool isL1 = wid >= 4;
    const int lr = lane & 15;           // A-row within tile / B-col (batch)
    const int lg = lane >> 4;           // lane group -> k-slot group
    const int b0 = blockIdx.x * NB;

    // ---- stage x transposed: x_lds2[t][b] (conflict-free step reads) ----
    {
        const float4* xs = (const float4*)(x + (size_t)b0 * TT);
        #pragma unroll
        for (int i = 0; i < 2; ++i) {
            int idx = i * NT + tid;          // 0..1023 float4s
            float4 v = xs[idx];
            int b  = idx >> 7;               // 128 float4 per row
            int t4 = (idx & 127) << 2;
            x_lds2[t4 + 0][b] = v.x;
            x_lds2[t4 + 1][b] = v.y;
            x_lds2[t4 + 2][b] = v.z;
            x_lds2[t4 + 3][b] = v.w;
        }
    }
    // ---- zero h buffers (h(-1) = 0) ----
    {
        int* hz = (int*)hbuf;                // 4096 ints
        #pragma unroll
        for (int i = 0; i < 8; ++i) hz[i * NT + tid] = 0;
    }

    // ---- per-wave static weights: A-fragments (hi/lo), bias, wx ----
    // Wave owns M-tiles {wloc, wloc+4, wloc+8, wloc+12} = gate j rows [64j+16w, +16).
    bf16x8 Ahi[16], Alo[16];
    float bias[16], wxv[16];
    float cst[4] = {0.f, 0.f, 0.f, 0.f};     // c-state, units base_u..base_u+3
    const int base_u = 16 * wloc + 4 * lg;   // C-layout unit base for this lane
    // frag write offset (ushorts): ((b) + 16*(u>>3))*8 + (u&7), 4 consecutive r
    const int woff = (lr + 16 * (base_u >> 3)) * 8 + (base_u & 7);
    const int fro  = lane * 8;               // frag read offset (ushorts)

    if (!isL1) {
        #pragma unroll
        for (int j = 0; j < 4; ++j) {
            const int row = j * 64 + 16 * wloc + lr;
            #pragma unroll
            for (int kt = 0; kt < 2; ++kt)
                split8(W_hh0 + row * H + kt * 32 + 8 * lg, Ahi[j * 2 + kt], Alo[j * 2 + kt]);
            const int rowc = j * 64 + base_u;
            #pragma unroll
            for (int r = 0; r < 4; ++r) {
                bias[j * 4 + r] = b_ih0[rowc + r] + b_hh0[rowc + r];
                wxv[j * 4 + r]  = W_ih0[rowc + r];
            }
        }
        #pragma unroll
        for (int i = 0; i < 8; ++i) { asm volatile("" : "+v"(Ahi[i])); asm volatile("" : "+v"(Alo[i])); }
        #pragma unroll
        for (int i = 0; i < 16; ++i) { asm volatile("" : "+v"(bias[i])); asm volatile("" : "+v"(wxv[i])); }
    } else {
        #pragma unroll
        for (int j = 0; j < 4; ++j) {
            const int row = j * 64 + 16 * wloc + lr;
            #pragma unroll
            for (int kt = 0; kt < 4; ++kt) {
                const float* p = (kt < 2) ? (W_ih1 + row * H + kt * 32 + 8 * lg)
                                          : (W_hh1 + row * H + (kt - 2) * 32 + 8 * lg);
                split8(p, Ahi[j * 4 + kt], Alo[j * 4 + kt]);
            }
            const int rowc = j * 64 + base_u;
            #pragma unroll
            for (int r = 0; r < 4; ++r)
                bias[j * 4 + r] = b_ih1[rowc + r] + b_hh1[rowc + r];
        }
        #pragma unroll
        for (int i = 0; i < 16; ++i) { asm volatile("" : "+v"(Ahi[i])); asm volatile("" : "+v"(Alo[i])); }
        #pragma unroll
        for (int i = 0; i < 16; ++i) { asm volatile("" : "+v"(bias[i])); }
    }

    __syncthreads();

    // ---- pipelined time loop: L0 computes h1(t); L1 computes h2(t-1) ----
    for (int t = 0; t <= TT; ++t) {
        if (!isL1) {
            if (t < TT) {
                const int rb = (t + 1) & 1;              // h1(t-1)
                const unsigned short* ph = &hbuf[0][rb][0][0];
                const unsigned short* pl = &hbuf[0][rb][1][0];
                bf16x8 Bh0 = *(const bf16x8*)(ph + fro);
                bf16x8 Bh1 = *(const bf16x8*)(ph + 512 + fro);
                bf16x8 Bl0 = *(const bf16x8*)(pl + fro);
                bf16x8 Bl1 = *(const bf16x8*)(pl + 512 + fro);
                const float xv = x_lds2[t][lane & 7];
                f32x4 acc[4];
                #pragma unroll
                for (int j = 0; j < 4; ++j)
                    #pragma unroll
                    for (int r = 0; r < 4; ++r)
                        acc[j][r] = fmaf(wxv[j * 4 + r], xv, bias[j * 4 + r]);
                #pragma unroll
                for (int j = 0; j < 4; ++j) {
                    MFMA(Ahi[j * 2 + 0], Bh0, acc[j]);
                    MFMA(Ahi[j * 2 + 0], Bl0, acc[j]);
                    MFMA(Alo[j * 2 + 0], Bh0, acc[j]);
                    MFMA(Ahi[j * 2 + 1], Bh1, acc[j]);
                    MFMA(Ahi[j * 2 + 1], Bl1, acc[j]);
                    MFMA(Alo[j * 2 + 1], Bh1, acc[j]);
                }
                unsigned short h_hi[4], h_lo[4];
                #pragma unroll
                for (int r = 0; r < 4; ++r) {
                    const float iv = sigm(acc[0][r]);
                    const float fv = sigm(acc[1][r]);
                    const float gv = tanh_fast(acc[2][r]);
                    const float ov = sigm(acc[3][r]);
                    cst[r] = fmaf(fv, cst[r], iv * gv);
                    const float hv = ov * tanh_fast(cst[r]);
                    h_hi[r] = f2bf(hv);
                    h_lo[r] = f2bf(hv - bf2f(h_hi[r]));
                }
                const int wb = t & 1;
                *(ushort4*)&hbuf[0][wb][0][woff] = make_ushort4(h_hi[0], h_hi[1], h_hi[2], h_hi[3]);
                *(ushort4*)&hbuf[0][wb][1][woff] = make_ushort4(h_lo[0], h_lo[1], h_lo[2], h_lo[3]);
            }
        } else {
            if (t >= 1) {
                const int rb1 = (t + 1) & 1;             // h1(t-1)
                const int rb2 = t & 1;                   // h2(t-2)
                const unsigned short* p1h = &hbuf[0][rb1][0][0];
                const unsigned short* p1l = &hbuf[0][rb1][1][0];
                const unsigned short* p2h = &hbuf[1][rb2][0][0];
                const unsigned short* p2l = &hbuf[1][rb2][1][0];
                bf16x8 Bh[4], Bl[4];
                Bh[0] = *(const bf16x8*)(p1h + fro);
                Bh[1] = *(const bf16x8*)(p1h + 512 + fro);
                Bh[2] = *(const bf16x8*)(p2h + fro);
                Bh[3] = *(const bf16x8*)(p2h + 512 + fro);
                Bl[0] = *(const bf16x8*)(p1l + fro);
                Bl[1] = *(const bf16x8*)(p1l + 512 + fro);
                Bl[2] = *(const bf16x8*)(p2l + fro);
                Bl[3] = *(const bf16x8*)(p2l + 512 + fro);
                f32x4 acc[4];
                #pragma unroll
                for (int j = 0; j < 4; ++j)
                    #pragma unroll
                    for (int r = 0; r < 4; ++r)
                        acc[j][r] = bias[j * 4 + r];
                #pragma unroll
                for (int j = 0; j < 4; ++j)
                    #pragma unroll
                    for (int kt = 0; kt < 4; ++kt) {
                        MFMA(Ahi[j * 4 + kt], Bh[kt], acc[j]);
                        MFMA(Ahi[j * 4 + kt], Bl[kt], acc[j]);
                        MFMA(Alo[j * 4 + kt], Bh[kt], acc[j]);
                    }
                unsigned short h_hi[4], h_lo[4];
                float hvv[4];
                #pragma unroll
                for (int r = 0; r < 4; ++r) {
                    const float iv = sigm(acc[0][r]);
                    const float fv = sigm(acc[1][r]);
                    const float gv = tanh_fast(acc[2][r]);
                    const float ov = sigm(acc[3][r]);
                    cst[r] = fmaf(fv, cst[r], iv * gv);
                    hvv[r] = ov * tanh_fast(cst[r]);
                    h_hi[r] = f2bf(hvv[r]);
                    h_lo[r] = f2bf(hvv[r] - bf2f(h_hi[r]));
                }
                const int wb = (t + 1) & 1;
                *(ushort4*)&hbuf[1][wb][0][woff] = make_ushort4(h_hi[0], h_hi[1], h_hi[2], h_hi[3]);
                *(ushort4*)&hbuf[1][wb][1][woff] = make_ushort4(h_lo[0], h_lo[1], h_lo[2], h_lo[3]);
                if (t == TT && lr < NB) {
                    float s = 0.f;
                    #pragma unroll
                    for (int r = 0; r < 4; ++r) s += fc_W[base_u + r] * hvv[r];
                    fc_part[(wid - 4) * 4 + lg][lr] = s;
                }
            }
        }
        __syncthreads();
    }

    // ---- final FC reduce (deterministic) ----
    if (tid < NB) {
        float s = fc_b[0];
        #pragma unroll
        for (int i = 0; i < 16; ++i) s += fc_part[i][tid];
        out[b0 + tid] = s;
    }
}

} // namespace

extern "C" void kernel_launch(void* const* d_in, const int* in_sizes, int n_in,
                              void* d_out, int out_size, void* d_ws, size_t ws_size,
                              hipStream_t stream)
{
    const float* x     = (const float*)d_in[0];
    const float* W_ih0 = (const float*)d_in[1];
    const float* W_hh0 = (const float*)d_in[2];
    const float* b_ih0 = (const float*)d_in[3];
    const float* b_hh0 = (const float*)d_in[4];
    const float* W_ih1 = (const float*)d_in[5];
    const float* W_hh1 = (const float*)d_in[6];
    const float* b_ih1 = (const float*)d_in[7];
    const float* b_hh1 = (const float*)d_in[8];
    const float* fc_W  = (const float*)d_in[9];
    const float* fc_b  = (const float*)d_in[10];
    float* out = (float*)d_out;

    const int B = in_sizes[0] / TT;          // 2048
    dim3 grid(B / NB), block(NT);            // 256 blocks x 512 threads
    hipLaunchKernelGGL(lstm2_mfma_kernel, grid, block, 0, stream,
                       x, W_ih0, W_hh0, b_ih0, b_hh0,
                       W_ih1, W_hh1, b_ih1, b_hh1, fc_W, fc_b, out);
}

// Round 4
// 599.151 us; speedup vs baseline: 3.3698x; 1.0256x over previous
//
#include <hip/hip_runtime.h>

namespace {

constexpr int TT = 512;   // timesteps
constexpr int H  = 64;    // hidden units per layer
constexpr int NB = 8;     // real batches per block (MFMA cols 8..15 mirror 0..7)
constexpr int NT = 512;   // 8 waves: 0-3 -> layer0, 4-7 -> layer1

typedef float  f32x4  __attribute__((ext_vector_type(4)));
typedef short  bf16x8 __attribute__((ext_vector_type(8)));

#define MFMA(A, B, C) (C) = __builtin_amdgcn_mfma_f32_16x16x32_bf16((A), (B), (C), 0, 0, 0)

__device__ __forceinline__ float exp2_hw(float x) {
    float r; asm("v_exp_f32 %0, %1" : "=v"(r) : "v"(x)); return r;
}
__device__ __forceinline__ float sigm(float z) {          // 1/(1+2^(-z*log2e))
    return __builtin_amdgcn_rcpf(1.0f + exp2_hw(-1.442695041f * z));
}
__device__ __forceinline__ float tanh_fast(float z) {     // 2*sigm(2z)-1, constant folded
    return fmaf(2.0f, __builtin_amdgcn_rcpf(1.0f + exp2_hw(-2.885390082f * z)), -1.0f);
}
__device__ __forceinline__ unsigned short f2bf(float f) {
    unsigned u = __float_as_uint(f);
    return (unsigned short)((u + 0x7fffu + ((u >> 16) & 1u)) >> 16);
}
__device__ __forceinline__ float bf2f(unsigned short s) {
    return __uint_as_float(((unsigned)s) << 16);
}
__device__ __forceinline__ void split8(const float* __restrict__ p, bf16x8& hi, bf16x8& lo) {
    float4 a = *(const float4*)p;
    float4 b = *(const float4*)(p + 4);
    float t[8] = {a.x, a.y, a.z, a.w, b.x, b.y, b.z, b.w};
    #pragma unroll
    for (int i = 0; i < 8; ++i) {
        unsigned short h = f2bf(t[i]);
        hi[i] = (short)h;
        lo[i] = (short)f2bf(t[i] - bf2f(h));
    }
}

// Counter sync: sum-condition c >= 4t with 4 waves/group enforces lockstep
// (skew<=1 in-flight) inside a group; cross-group ring depth allows stagger.
__device__ __forceinline__ void waitge(int* c, int v) {
    while (__hip_atomic_load(c, __ATOMIC_ACQUIRE, __HIP_MEMORY_SCOPE_WORKGROUP) < v) {}
}
__device__ __forceinline__ void signal(int* c) {
    if ((threadIdx.x & 63) == 0)
        (void)__hip_atomic_fetch_add(c, 1, __ATOMIC_RELEASE, __HIP_MEMORY_SCOPE_WORKGROUP);
}

__global__ __launch_bounds__(NT) void lstm2_mfma_kernel(
    const float* __restrict__ x,
    const float* __restrict__ W_ih0, const float* __restrict__ W_hh0,
    const float* __restrict__ b_ih0, const float* __restrict__ b_hh0,
    const float* __restrict__ W_ih1, const float* __restrict__ W_hh1,
    const float* __restrict__ b_ih1, const float* __restrict__ b_hh1,
    const float* __restrict__ fc_W,  const float* __restrict__ fc_b,
    float* __restrict__ out)
{
    // h1 ring (depth 4) lets L0 run up to 3 steps ahead of L1.
    __shared__ alignas(16) unsigned short h1ring[4][2][1024];   // 16 KB [slot][hi/lo][frag]
    __shared__ alignas(16) unsigned short h2buf[2][2][1024];    //  8 KB
    __shared__ float x_lds2[TT][NB];                            // 16 KB, [t][b]
    __shared__ float fc_part[16][NB];
    __shared__ int c0, c1;            // completed-iteration counters (L0, L1)

    const int tid  = threadIdx.x;
    const int lane = tid & 63;
    const int wid  = tid >> 6;          // 0..7
    const int wloc = wid & 3;
    const bool isL1 = wid >= 4;
    const int lr = lane & 15;           // A-row within tile / B-col (batch)
    const int lg = lane >> 4;
    const int b0 = blockIdx.x * NB;

    // ---- stage x transposed ----
    {
        const float4* xs = (const float4*)(x + (size_t)b0 * TT);
        #pragma unroll
        for (int i = 0; i < 2; ++i) {
            int idx = i * NT + tid;
            float4 v = xs[idx];
            int b  = idx >> 7;
            int t4 = (idx & 127) << 2;
            x_lds2[t4 + 0][b] = v.x;
            x_lds2[t4 + 1][b] = v.y;
            x_lds2[t4 + 2][b] = v.z;
            x_lds2[t4 + 3][b] = v.w;
        }
    }
    // ---- zero h buffers ----
    {
        int* hz = (int*)h1ring;          // 4096 ints
        #pragma unroll
        for (int i = 0; i < 8; ++i) hz[i * NT + tid] = 0;
        int* h2z = (int*)h2buf;          // 2048 ints
        #pragma unroll
        for (int i = 0; i < 4; ++i) h2z[i * NT + tid] = 0;
    }
    if (tid == 0) { c0 = 0; c1 = 0; }

    // ---- per-wave static weights ----
    bf16x8 Ahi[16], Alo[16];
    float bias[16], wxv[16];
    float cst[4] = {0.f, 0.f, 0.f, 0.f};
    const int base_u = 16 * wloc + 4 * lg;
    const int woff = (lr + 16 * (base_u >> 3)) * 8 + (base_u & 7);  // ushort idx
    const int fro  = lane * 8;

    if (!isL1) {
        #pragma unroll
        for (int j = 0; j < 4; ++j) {
            const int row = j * 64 + 16 * wloc + lr;
            #pragma unroll
            for (int kt = 0; kt < 2; ++kt)
                split8(W_hh0 + row * H + kt * 32 + 8 * lg, Ahi[j * 2 + kt], Alo[j * 2 + kt]);
            const int rowc = j * 64 + base_u;
            #pragma unroll
            for (int r = 0; r < 4; ++r) {
                bias[j * 4 + r] = b_ih0[rowc + r] + b_hh0[rowc + r];
                wxv[j * 4 + r]  = W_ih0[rowc + r];
            }
        }
        #pragma unroll
        for (int i = 0; i < 8; ++i) { asm volatile("" : "+v"(Ahi[i])); asm volatile("" : "+v"(Alo[i])); }
        #pragma unroll
        for (int i = 0; i < 16; ++i) { asm volatile("" : "+v"(bias[i])); asm volatile("" : "+v"(wxv[i])); }
    } else {
        #pragma unroll
        for (int j = 0; j < 4; ++j) {
            const int row = j * 64 + 16 * wloc + lr;
            #pragma unroll
            for (int kt = 0; kt < 4; ++kt) {
                const float* p = (kt < 2) ? (W_ih1 + row * H + kt * 32 + 8 * lg)
                                          : (W_hh1 + row * H + (kt - 2) * 32 + 8 * lg);
                split8(p, Ahi[j * 4 + kt], Alo[j * 4 + kt]);
            }
            const int rowc = j * 64 + base_u;
            #pragma unroll
            for (int r = 0; r < 4; ++r)
                bias[j * 4 + r] = b_ih1[rowc + r] + b_hh1[rowc + r];
        }
        #pragma unroll
        for (int i = 0; i < 16; ++i) { asm volatile("" : "+v"(Ahi[i])); asm volatile("" : "+v"(Alo[i])); }
        #pragma unroll
        for (int i = 0; i < 16; ++i) { asm volatile("" : "+v"(bias[i])); }
    }

    __syncthreads();   // x staged, buffers zeroed, counters init

    if (!isL1) {
        // ================= L0 group: computes h1(t), t = 0..TT-1 =================
        for (int t = 0; t < TT; ++t) {
            waitge(&c0, 4 * t);                       // peers done t-1
            if (t >= 4) waitge(&c1, 4 * (t - 3));     // ring slot t&3 free
            const unsigned short* ph = &h1ring[(t - 1) & 3][0][0];
            const unsigned short* pl = &h1ring[(t - 1) & 3][1][0];
            bf16x8 Bh0 = *(const bf16x8*)(ph + fro);
            bf16x8 Bh1 = *(const bf16x8*)(ph + 512 + fro);
            bf16x8 Bl0 = *(const bf16x8*)(pl + fro);
            bf16x8 Bl1 = *(const bf16x8*)(pl + 512 + fro);
            const float xv = x_lds2[t][lane & 7];
            f32x4 acc[4];
            #pragma unroll
            for (int j = 0; j < 4; ++j)
                #pragma unroll
                for (int r = 0; r < 4; ++r)
                    acc[j][r] = fmaf(wxv[j * 4 + r], xv, bias[j * 4 + r]);
            __builtin_amdgcn_s_setprio(1);
            #pragma unroll
            for (int j = 0; j < 4; ++j) {
                MFMA(Ahi[j * 2 + 0], Bh0, acc[j]);
                MFMA(Ahi[j * 2 + 0], Bl0, acc[j]);
                MFMA(Alo[j * 2 + 0], Bh0, acc[j]);
                MFMA(Ahi[j * 2 + 1], Bh1, acc[j]);
                MFMA(Ahi[j * 2 + 1], Bl1, acc[j]);
                MFMA(Alo[j * 2 + 1], Bh1, acc[j]);
            }
            __builtin_amdgcn_s_setprio(0);
            float hvv[4];
            #pragma unroll
            for (int r = 0; r < 4; ++r) {
                const float iv = sigm(acc[0][r]);
                const float fv = sigm(acc[1][r]);
                const float gv = tanh_fast(acc[2][r]);
                const float ov = sigm(acc[3][r]);
                cst[r] = fmaf(fv, cst[r], iv * gv);
                hvv[r] = ov * tanh_fast(cst[r]);
            }
            unsigned p01, p23, q01, q23;
            asm("v_cvt_pk_bf16_f32 %0, %1, %2" : "=v"(p01) : "v"(hvv[0]), "v"(hvv[1]));
            asm("v_cvt_pk_bf16_f32 %0, %1, %2" : "=v"(p23) : "v"(hvv[2]), "v"(hvv[3]));
            const float r0 = hvv[0] - __uint_as_float(p01 << 16);
            const float r1 = hvv[1] - __uint_as_float(p01 & 0xffff0000u);
            const float r2 = hvv[2] - __uint_as_float(p23 << 16);
            const float r3 = hvv[3] - __uint_as_float(p23 & 0xffff0000u);
            asm("v_cvt_pk_bf16_f32 %0, %1, %2" : "=v"(q01) : "v"(r0), "v"(r1));
            asm("v_cvt_pk_bf16_f32 %0, %1, %2" : "=v"(q23) : "v"(r2), "v"(r3));
            *(uint2*)&h1ring[t & 3][0][woff] = make_uint2(p01, p23);
            *(uint2*)&h1ring[t & 3][1][woff] = make_uint2(q01, q23);
            signal(&c0);
        }
    } else {
        // ================= L1 group: iter t computes h2(t-1), t = 1..TT =================
        for (int t = 1; t <= TT; ++t) {
            waitge(&c1, 4 * (t - 1));                 // peers done t-1 (h2(t-2) ready)
            waitge(&c0, 4 * t);                       // h1(t-1) ready
            const unsigned short* p1h = &h1ring[(t - 1) & 3][0][0];
            const unsigned short* p1l = &h1ring[(t - 1) & 3][1][0];
            const unsigned short* p2h = &h2buf[(t - 2) & 1][0][0];
            const unsigned short* p2l = &h2buf[(t - 2) & 1][1][0];
            bf16x8 Bh[4], Bl[4];
            Bh[0] = *(const bf16x8*)(p1h + fro);
            Bh[1] = *(const bf16x8*)(p1h + 512 + fro);
            Bh[2] = *(const bf16x8*)(p2h + fro);
            Bh[3] = *(const bf16x8*)(p2h + 512 + fro);
            Bl[0] = *(const bf16x8*)(p1l + fro);
            Bl[1] = *(const bf16x8*)(p1l + 512 + fro);
            Bl[2] = *(const bf16x8*)(p2l + fro);
            Bl[3] = *(const bf16x8*)(p2l + 512 + fro);
            f32x4 acc[4];
            #pragma unroll
            for (int j = 0; j < 4; ++j)
                #pragma unroll
                for (int r = 0; r < 4; ++r)
                    acc[j][r] = bias[j * 4 + r];
            __builtin_amdgcn_s_setprio(1);
            #pragma unroll
            for (int j = 0; j < 4; ++j)
                #pragma unroll
                for (int kt = 0; kt < 4; ++kt) {
                    MFMA(Ahi[j * 4 + kt], Bh[kt], acc[j]);
                    MFMA(Ahi[j * 4 + kt], Bl[kt], acc[j]);
                    MFMA(Alo[j * 4 + kt], Bh[kt], acc[j]);
                }
            __builtin_amdgcn_s_setprio(0);
            float hvv[4];
            #pragma unroll
            for (int r = 0; r < 4; ++r) {
                const float iv = sigm(acc[0][r]);
                const float fv = sigm(acc[1][r]);
                const float gv = tanh_fast(acc[2][r]);
                const float ov = sigm(acc[3][r]);
                cst[r] = fmaf(fv, cst[r], iv * gv);
                hvv[r] = ov * tanh_fast(cst[r]);
            }
            unsigned p01, p23, q01, q23;
            asm("v_cvt_pk_bf16_f32 %0, %1, %2" : "=v"(p01) : "v"(hvv[0]), "v"(hvv[1]));
            asm("v_cvt_pk_bf16_f32 %0, %1, %2" : "=v"(p23) : "v"(hvv[2]), "v"(hvv[3]));
            const float r0 = hvv[0] - __uint_as_float(p01 << 16);
            const float r1 = hvv[1] - __uint_as_float(p01 & 0xffff0000u);
            const float r2 = hvv[2] - __uint_as_float(p23 << 16);
            const float r3 = hvv[3] - __uint_as_float(p23 & 0xffff0000u);
            asm("v_cvt_pk_bf16_f32 %0, %1, %2" : "=v"(q01) : "v"(r0), "v"(r1));
            asm("v_cvt_pk_bf16_f32 %0, %1, %2" : "=v"(q23) : "v"(r2), "v"(r3));
            *(uint2*)&h2buf[(t - 1) & 1][0][woff] = make_uint2(p01, p23);
            *(uint2*)&h2buf[(t - 1) & 1][1][woff] = make_uint2(q01, q23);
            if (t == TT && lr < NB) {
                float s = 0.f;
                #pragma unroll
                for (int r = 0; r < 4; ++r) s += fc_W[base_u + r] * hvv[r];
                fc_part[(wid - 4) * 4 + lg][lr] = s;
            }
            signal(&c1);
        }
    }

    __syncthreads();

    // ---- final FC reduce (deterministic) ----
    if (tid < NB) {
        float s = fc_b[0];
        #pragma unroll
        for (int i = 0; i < 16; ++i) s += fc_part[i][tid];
        out[b0 + tid] = s;
    }
}

} // namespace

extern "C" void kernel_launch(void* const* d_in, const int* in_sizes, int n_in,
                              void* d_out, int out_size, void* d_ws, size_t ws_size,
                              hipStream_t stream)
{
    const float* x     = (const float*)d_in[0];
    const float* W_ih0 = (const float*)d_in[1];
    const float* W_hh0 = (const float*)d_in[2];
    const float* b_ih0 = (const float*)d_in[3];
    const float* b_hh0 = (const float*)d_in[4];
    const float* W_ih1 = (const float*)d_in[5];
    const float* W_hh1 = (const float*)d_in[6];
    const float* b_ih1 = (const float*)d_in[7];
    const float* b_hh1 = (const float*)d_in[8];
    const float* fc_W  = (const float*)d_in[9];
    const float* fc_b  = (const float*)d_in[10];
    float* out = (float*)d_out;

    const int B = in_sizes[0] / TT;          // 2048
    dim3 grid(B / NB), block(NT);            // 256 blocks x 512 threads
    hipLaunchKernelGGL(lstm2_mfma_kernel, grid, block, 0, stream,
                       x, W_ih0, W_hh0, b_ih0, b_hh0,
                       W_ih1, W_hh1, b_ih1, b_hh1, fc_W, fc_b, out);
}

// Round 5
// 455.711 us; speedup vs baseline: 4.4305x; 1.3148x over previous
//
#include <hip/hip_runtime.h>

namespace {

constexpr int TT = 512;   // timesteps
constexpr int H  = 64;    // hidden units per layer
constexpr int NB = 8;     // real batches per block (MFMA cols 8..15 mirror 0..7)
constexpr int NT = 512;   // 8 waves: 0-3 -> layer0, 4-7 -> layer1
constexpr float L2E = 1.442695041f;

typedef float  f32x4  __attribute__((ext_vector_type(4)));
typedef short  bf16x8 __attribute__((ext_vector_type(8)));

#define MFMA(A, B, C) (C) = __builtin_amdgcn_mfma_f32_16x16x32_bf16((A), (B), (C), 0, 0, 0)

__device__ __forceinline__ float exp2_hw(float x) {
    float r; asm("v_exp_f32 %0, %1" : "=v"(r) : "v"(x)); return r;
}
// gates arrive pre-scaled by -log2e (sigmoid rows) / -2log2e (tanh rows)
__device__ __forceinline__ float sigm_pre(float zs) {     // zs = -log2e * z
    return __builtin_amdgcn_rcpf(1.0f + exp2_hw(zs));
}
__device__ __forceinline__ float tanh_pre(float zs) {     // zs = -2*log2e * z
    return fmaf(2.0f, __builtin_amdgcn_rcpf(1.0f + exp2_hw(zs)), -1.0f);
}
__device__ __forceinline__ float tanh_fast(float z) {     // unscaled input (c-state)
    return fmaf(2.0f, __builtin_amdgcn_rcpf(1.0f + exp2_hw(-2.885390082f * z)), -1.0f);
}
__device__ __forceinline__ unsigned short f2bf(float f) {
    unsigned u = __float_as_uint(f);
    return (unsigned short)((u + 0x7fffu + ((u >> 16) & 1u)) >> 16);
}
__device__ __forceinline__ float bf2f(unsigned short s) {
    return __uint_as_float(((unsigned)s) << 16);
}
// Load 8 consecutive floats, scale, split into hi/lo bf16 fragments.
__device__ __forceinline__ void split8s(const float* __restrict__ p, float s,
                                        bf16x8& hi, bf16x8& lo) {
    float4 a = *(const float4*)p;
    float4 b = *(const float4*)(p + 4);
    float t[8] = {a.x * s, a.y * s, a.z * s, a.w * s, b.x * s, b.y * s, b.z * s, b.w * s};
    #pragma unroll
    for (int i = 0; i < 8; ++i) {
        unsigned short h = f2bf(t[i]);
        hi[i] = (short)h;
        lo[i] = (short)f2bf(t[i] - bf2f(h));
    }
}

__device__ __forceinline__ void waitge(int* c, int v) {
    while (__hip_atomic_load(c, __ATOMIC_ACQUIRE, __HIP_MEMORY_SCOPE_WORKGROUP) < v) {}
}
__device__ __forceinline__ void signal(int* c) {
    if ((threadIdx.x & 63) == 0)
        (void)__hip_atomic_fetch_add(c, 1, __ATOMIC_RELEASE, __HIP_MEMORY_SCOPE_WORKGROUP);
}

__global__ __launch_bounds__(NT) void lstm2_mfma_kernel(
    const float* __restrict__ x,
    const float* __restrict__ W_ih0, const float* __restrict__ W_hh0,
    const float* __restrict__ b_ih0, const float* __restrict__ b_hh0,
    const float* __restrict__ W_ih1, const float* __restrict__ W_hh1,
    const float* __restrict__ b_ih1, const float* __restrict__ b_hh1,
    const float* __restrict__ fc_W,  const float* __restrict__ fc_b,
    float* __restrict__ out)
{
    __shared__ alignas(16) unsigned short h1ring[4][2][1024];   // 16 KB [slot][hi/lo][frag]
    __shared__ alignas(16) unsigned short h2buf[2][2][1024];    //  8 KB
    __shared__ float x_lds2[TT][NB];                            // 16 KB, [t][b]
    __shared__ float fc_part[32][NB];
    __shared__ int c0, c1c, c1d;

    const int tid  = threadIdx.x;
    const int lane = tid & 63;
    const int wid  = tid >> 6;          // 0..7
    const int wloc = wid & 3;
    const bool isL1 = wid >= 4;
    const int lr = lane & 15;           // A-row within tile / B-col (batch, mod 8)
    const int lg = lane >> 4;
    const int b0 = blockIdx.x * NB;
    const bool lo8 = (lr < 8);
    const int rb = lo8 ? 0 : 2;         // r-split: which 2 acc slots this lane activates

    // ---- stage x transposed ----
    {
        const float4* xs = (const float4*)(x + (size_t)b0 * TT);
        #pragma unroll
        for (int i = 0; i < 2; ++i) {
            int idx = i * NT + tid;
            float4 v = xs[idx];
            int b  = idx >> 7;
            int t4 = (idx & 127) << 2;
            x_lds2[t4 + 0][b] = v.x;
            x_lds2[t4 + 1][b] = v.y;
            x_lds2[t4 + 2][b] = v.z;
            x_lds2[t4 + 3][b] = v.w;
        }
    }
    // ---- zero h buffers ----
    {
        int* hz = (int*)h1ring;
        #pragma unroll
        for (int i = 0; i < 8; ++i) hz[i * NT + tid] = 0;
        int* h2z = (int*)h2buf;
        #pragma unroll
        for (int i = 0; i < 4; ++i) h2z[i * NT + tid] = 0;
    }
    if (tid == 0) { c0 = 0; c1c = 0; c1d = 0; }

    // ---- per-wave static weights (pre-scaled by -log2e / -2log2e per gate row) ----
    bf16x8 Ahi[16], Alo[16];
    float bias[16], wxv[16];
    float cst0 = 0.f, cst1 = 0.f;            // c-state for this lane's 2 units
    const int base_u = 16 * wloc + 4 * lg;
    const int u0 = base_u + rb;              // first of this lane's 2 units
    // B-frag ushort idx of (unit u0, col lr&7):
    const int wo  = ((lr & 7) + 16 * (base_u >> 3)) * 8 + (base_u & 7) + rb;
    const int fro = lane * 8;

    if (!isL1) {
        #pragma unroll
        for (int j = 0; j < 4; ++j) {
            const float sj = (j == 2) ? (-2.0f * L2E) : (-L2E);
            const int row = j * 64 + 16 * wloc + lr;
            #pragma unroll
            for (int kt = 0; kt < 2; ++kt)
                split8s(W_hh0 + row * H + kt * 32 + 8 * lg, sj, Ahi[j * 2 + kt], Alo[j * 2 + kt]);
            const int rowc = j * 64 + base_u;
            #pragma unroll
            for (int r = 0; r < 4; ++r) {
                bias[j * 4 + r] = (b_ih0[rowc + r] + b_hh0[rowc + r]) * sj;
                wxv[j * 4 + r]  = W_ih0[rowc + r] * sj;
            }
        }
        #pragma unroll
        for (int i = 0; i < 8; ++i) { asm volatile("" : "+v"(Ahi[i])); asm volatile("" : "+v"(Alo[i])); }
        #pragma unroll
        for (int i = 0; i < 16; ++i) { asm volatile("" : "+v"(bias[i])); asm volatile("" : "+v"(wxv[i])); }
    } else {
        #pragma unroll
        for (int j = 0; j < 4; ++j) {
            const float sj = (j == 2) ? (-2.0f * L2E) : (-L2E);
            const int row = j * 64 + 16 * wloc + lr;
            #pragma unroll
            for (int kt = 0; kt < 4; ++kt) {
                const float* p = (kt < 2) ? (W_ih1 + row * H + kt * 32 + 8 * lg)
                                          : (W_hh1 + row * H + (kt - 2) * 32 + 8 * lg);
                split8s(p, sj, Ahi[j * 4 + kt], Alo[j * 4 + kt]);
            }
            const int rowc = j * 64 + base_u;
            #pragma unroll
            for (int r = 0; r < 4; ++r)
                bias[j * 4 + r] = (b_ih1[rowc + r] + b_hh1[rowc + r]) * sj;
        }
        #pragma unroll
        for (int i = 0; i < 16; ++i) { asm volatile("" : "+v"(Ahi[i])); asm volatile("" : "+v"(Alo[i])); }
        #pragma unroll
        for (int i = 0; i < 16; ++i) { asm volatile("" : "+v"(bias[i])); }
    }

    __syncthreads();

    if (!isL1) {
        // ============ L0: computes h1(t). Ring gate = L1's MFMA-end (c1c) ============
        for (int t = 0; t < TT; ++t) {
            waitge(&c0, 4 * t);                        // peers done t-1
            if (t >= 4) waitge(&c1c, 4 * (t - 3));     // ring slot t&3 consumed by L1
            const unsigned short* ph = &h1ring[(t - 1) & 3][0][0];
            const unsigned short* pl = &h1ring[(t - 1) & 3][1][0];
            bf16x8 Bh0 = *(const bf16x8*)(ph + fro);
            bf16x8 Bh1 = *(const bf16x8*)(ph + 512 + fro);
            bf16x8 Bl0 = *(const bf16x8*)(pl + fro);
            bf16x8 Bl1 = *(const bf16x8*)(pl + 512 + fro);
            const float xv = x_lds2[t][lane & 7];
            f32x4 acc[4];
            #pragma unroll
            for (int j = 0; j < 4; ++j)
                #pragma unroll
                for (int r = 0; r < 4; ++r)
                    acc[j][r] = fmaf(wxv[j * 4 + r], xv, bias[j * 4 + r]);
            __builtin_amdgcn_s_setprio(1);
            #pragma unroll
            for (int j = 0; j < 4; ++j) {
                MFMA(Ahi[j * 2 + 0], Bh0, acc[j]);
                MFMA(Ahi[j * 2 + 0], Bl0, acc[j]);
                MFMA(Alo[j * 2 + 0], Bh0, acc[j]);
                MFMA(Ahi[j * 2 + 1], Bh1, acc[j]);
                MFMA(Ahi[j * 2 + 1], Bl1, acc[j]);
                MFMA(Alo[j * 2 + 1], Bh1, acc[j]);
            }
            __builtin_amdgcn_s_setprio(0);
            // r-split: this lane activates only its 2 units (dup cols carry the data)
            const float zi0 = lo8 ? acc[0][0] : acc[0][2];
            const float zi1 = lo8 ? acc[0][1] : acc[0][3];
            const float zf0 = lo8 ? acc[1][0] : acc[1][2];
            const float zf1 = lo8 ? acc[1][1] : acc[1][3];
            const float zg0 = lo8 ? acc[2][0] : acc[2][2];
            const float zg1 = lo8 ? acc[2][1] : acc[2][3];
            const float zo0 = lo8 ? acc[3][0] : acc[3][2];
            const float zo1 = lo8 ? acc[3][1] : acc[3][3];
            cst0 = fmaf(sigm_pre(zf0), cst0, sigm_pre(zi0) * tanh_pre(zg0));
            cst1 = fmaf(sigm_pre(zf1), cst1, sigm_pre(zi1) * tanh_pre(zg1));
            const float hv0 = sigm_pre(zo0) * tanh_fast(cst0);
            const float hv1 = sigm_pre(zo1) * tanh_fast(cst1);
            unsigned p, q;
            asm("v_cvt_pk_bf16_f32 %0, %1, %2" : "=v"(p) : "v"(hv0), "v"(hv1));
            const float r0 = hv0 - __uint_as_float(p << 16);
            const float r1 = hv1 - __uint_as_float(p & 0xffff0000u);
            asm("v_cvt_pk_bf16_f32 %0, %1, %2" : "=v"(q) : "v"(r0), "v"(r1));
            *(unsigned*)&h1ring[t & 3][0][wo]      = p;
            *(unsigned*)&h1ring[t & 3][0][wo + 64] = p;    // col+8 duplicate
            *(unsigned*)&h1ring[t & 3][1][wo]      = q;
            *(unsigned*)&h1ring[t & 3][1][wo + 64] = q;
            signal(&c0);
        }
    } else {
        // ============ L1: iter t computes h2(t-1) ============
        for (int t = 1; t <= TT; ++t) {
            waitge(&c1d, 4 * (t - 1));                // peers' h2(t-2) written
            waitge(&c0, 4 * t);                       // h1(t-1) ready (ring: rarely binds)
            const unsigned short* p1h = &h1ring[(t - 1) & 3][0][0];
            const unsigned short* p1l = &h1ring[(t - 1) & 3][1][0];
            const unsigned short* p2h = &h2buf[(t - 2) & 1][0][0];
            const unsigned short* p2l = &h2buf[(t - 2) & 1][1][0];
            bf16x8 Bh[4], Bl[4];
            Bh[0] = *(const bf16x8*)(p1h + fro);
            Bh[1] = *(const bf16x8*)(p1h + 512 + fro);
            Bh[2] = *(const bf16x8*)(p2h + fro);
            Bh[3] = *(const bf16x8*)(p2h + 512 + fro);
            Bl[0] = *(const bf16x8*)(p1l + fro);
            Bl[1] = *(const bf16x8*)(p1l + 512 + fro);
            Bl[2] = *(const bf16x8*)(p2l + fro);
            Bl[3] = *(const bf16x8*)(p2l + 512 + fro);
            f32x4 acc[4];
            #pragma unroll
            for (int j = 0; j < 4; ++j)
                #pragma unroll
                for (int r = 0; r < 4; ++r)
                    acc[j][r] = bias[j * 4 + r];
            __builtin_amdgcn_s_setprio(1);
            #pragma unroll
            for (int j = 0; j < 4; ++j)
                #pragma unroll
                for (int kt = 0; kt < 4; ++kt) {
                    MFMA(Ahi[j * 4 + kt], Bh[kt], acc[j]);
                    MFMA(Ahi[j * 4 + kt], Bl[kt], acc[j]);
                    MFMA(Alo[j * 4 + kt], Bh[kt], acc[j]);
                }
            __builtin_amdgcn_s_setprio(0);
            // early ring-consume signal: releases L0 at our MFMA-end -> anti-phase
            __builtin_amdgcn_sched_barrier(0);
            signal(&c1c);
            const float zi0 = lo8 ? acc[0][0] : acc[0][2];
            const float zi1 = lo8 ? acc[0][1] : acc[0][3];
            const float zf0 = lo8 ? acc[1][0] : acc[1][2];
            const float zf1 = lo8 ? acc[1][1] : acc[1][3];
            const float zg0 = lo8 ? acc[2][0] : acc[2][2];
            const float zg1 = lo8 ? acc[2][1] : acc[2][3];
            const float zo0 = lo8 ? acc[3][0] : acc[3][2];
            const float zo1 = lo8 ? acc[3][1] : acc[3][3];
            cst0 = fmaf(sigm_pre(zf0), cst0, sigm_pre(zi0) * tanh_pre(zg0));
            cst1 = fmaf(sigm_pre(zf1), cst1, sigm_pre(zi1) * tanh_pre(zg1));
            const float hv0 = sigm_pre(zo0) * tanh_fast(cst0);
            const float hv1 = sigm_pre(zo1) * tanh_fast(cst1);
            unsigned p, q;
            asm("v_cvt_pk_bf16_f32 %0, %1, %2" : "=v"(p) : "v"(hv0), "v"(hv1));
            const float r0 = hv0 - __uint_as_float(p << 16);
            const float r1 = hv1 - __uint_as_float(p & 0xffff0000u);
            asm("v_cvt_pk_bf16_f32 %0, %1, %2" : "=v"(q) : "v"(r0), "v"(r1));
            *(unsigned*)&h2buf[(t - 1) & 1][0][wo]      = p;
            *(unsigned*)&h2buf[(t - 1) & 1][0][wo + 64] = p;
            *(unsigned*)&h2buf[(t - 1) & 1][1][wo]      = q;
            *(unsigned*)&h2buf[(t - 1) & 1][1][wo + 64] = q;
            if (t == TT) {
                const float s = fc_W[u0] * hv0 + fc_W[u0 + 1] * hv1;
                fc_part[(wid - 4) * 8 + lg * 2 + (lo8 ? 0 : 1)][lr & 7] = s;
            }
            signal(&c1d);
        }
    }

    __syncthreads();

    // ---- final FC reduce (deterministic) ----
    if (tid < NB) {
        float s = fc_b[0];
        #pragma unroll
        for (int i = 0; i < 32; ++i) s += fc_part[i][tid];
        out[b0 + tid] = s;
    }
}

} // namespace

extern "C" void kernel_launch(void* const* d_in, const int* in_sizes, int n_in,
                              void* d_out, int out_size, void* d_ws, size_t ws_size,
                              hipStream_t stream)
{
    const float* x     = (const float*)d_in[0];
    const float* W_ih0 = (const float*)d_in[1];
    const float* W_hh0 = (const float*)d_in[2];
    const float* b_ih0 = (const float*)d_in[3];
    const float* b_hh0 = (const float*)d_in[4];
    const float* W_ih1 = (const float*)d_in[5];
    const float* W_hh1 = (const float*)d_in[6];
    const float* b_ih1 = (const float*)d_in[7];
    const float* b_hh1 = (const float*)d_in[8];
    const float* fc_W  = (const float*)d_in[9];
    const float* fc_b  = (const float*)d_in[10];
    float* out = (float*)d_out;

    const int B = in_sizes[0] / TT;          // 2048
    dim3 grid(B / NB), block(NT);            // 256 blocks x 512 threads
    hipLaunchKernelGGL(lstm2_mfma_kernel, grid, block, 0, stream,
                       x, W_ih0, W_hh0, b_ih0, b_hh0,
                       W_ih1, W_hh1, b_ih1, b_hh1, fc_W, fc_b, out);
}

// Round 6
// 440.329 us; speedup vs baseline: 4.5852x; 1.0349x over previous
//
#include <hip/hip_runtime.h>

namespace {

constexpr int TT = 512;   // timesteps
constexpr int H  = 64;    // hidden units per layer
constexpr int NB = 8;     // real batches per block; MFMA cols 8..15 carry h_lo
constexpr int NT = 512;   // 8 waves: 0-3 -> layer0, 4-7 -> layer1
constexpr float L2E = 1.442695041f;

typedef float  f32x4  __attribute__((ext_vector_type(4)));
typedef short  bf16x8 __attribute__((ext_vector_type(8)));

#define MFMA(A, B, C) (C) = __builtin_amdgcn_mfma_f32_16x16x32_bf16((A), (B), (C), 0, 0, 0)

__device__ __forceinline__ float exp2_hw(float x) {
    float r; asm("v_exp_f32 %0, %1" : "=v"(r) : "v"(x)); return r;
}
__device__ __forceinline__ float sigm_pre(float zs) {     // zs = -log2e * z
    return __builtin_amdgcn_rcpf(1.0f + exp2_hw(zs));
}
__device__ __forceinline__ float tanh_pre(float zs) {     // zs = -2*log2e * z
    return fmaf(2.0f, __builtin_amdgcn_rcpf(1.0f + exp2_hw(zs)), -1.0f);
}
__device__ __forceinline__ float tanh_fast(float z) {     // unscaled input (c-state)
    return fmaf(2.0f, __builtin_amdgcn_rcpf(1.0f + exp2_hw(-2.885390082f * z)), -1.0f);
}
__device__ __forceinline__ unsigned short f2bf(float f) {
    unsigned u = __float_as_uint(f);
    return (unsigned short)((u + 0x7fffu + ((u >> 16) & 1u)) >> 16);
}
__device__ __forceinline__ float bf2f(unsigned short s) {
    return __uint_as_float(((unsigned)s) << 16);
}
__device__ __forceinline__ void split8s(const float* __restrict__ p, float s,
                                        bf16x8& hi, bf16x8& lo) {
    float4 a = *(const float4*)p;
    float4 b = *(const float4*)(p + 4);
    float t[8] = {a.x * s, a.y * s, a.z * s, a.w * s, b.x * s, b.y * s, b.z * s, b.w * s};
    #pragma unroll
    for (int i = 0; i < 8; ++i) {
        unsigned short h = f2bf(t[i]);
        hi[i] = (short)h;
        lo[i] = (short)f2bf(t[i] - bf2f(h));
    }
}
// lane c <-> lane c^8 exchange (within 32-lane groups) on the DS pipe
__device__ __forceinline__ float xor8(float v) {
    return __int_as_float(__builtin_amdgcn_ds_swizzle(__float_as_int(v), 0x201F));
}

__device__ __forceinline__ void waitge(int* c, int v) {
    while (__hip_atomic_load(c, __ATOMIC_ACQUIRE, __HIP_MEMORY_SCOPE_WORKGROUP) < v) {}
}
// for long waits: stop polluting issue slots while spinning
__device__ __forceinline__ void waitge_sleep(int* c, int v) {
    if (__hip_atomic_load(c, __ATOMIC_ACQUIRE, __HIP_MEMORY_SCOPE_WORKGROUP) >= v) return;
    do { __builtin_amdgcn_s_sleep(1); }
    while (__hip_atomic_load(c, __ATOMIC_ACQUIRE, __HIP_MEMORY_SCOPE_WORKGROUP) < v);
}
__device__ __forceinline__ void signal(int* c) {
    if ((threadIdx.x & 63) == 0)
        (void)__hip_atomic_fetch_add(c, 1, __ATOMIC_RELEASE, __HIP_MEMORY_SCOPE_WORKGROUP);
}

__global__ __launch_bounds__(NT) void lstm2_mfma_kernel(
    const float* __restrict__ x,
    const float* __restrict__ W_ih0, const float* __restrict__ W_hh0,
    const float* __restrict__ b_ih0, const float* __restrict__ b_hh0,
    const float* __restrict__ W_ih1, const float* __restrict__ W_hh1,
    const float* __restrict__ b_ih1, const float* __restrict__ b_hh1,
    const float* __restrict__ fc_W,  const float* __restrict__ fc_b,
    float* __restrict__ out)
{
    // single frag buffer per slot: cols 0-7 = h_hi(b0..7), cols 8-15 = h_lo(b0..7)
    __shared__ alignas(16) unsigned short h1ring[4][1024];   // 8 KB
    __shared__ alignas(16) unsigned short h2buf[2][1024];    // 4 KB
    __shared__ float x_lds2[TT][NB];                         // 16 KB, [t][b]
    __shared__ float fc_part[32][NB];
    __shared__ int c0, c1c, c1d;

    const int tid  = threadIdx.x;
    const int lane = tid & 63;
    const int wid  = tid >> 6;          // 0..7
    const int wloc = wid & 3;
    const bool isL1 = wid >= 4;
    const int lr = lane & 15;           // col: batch (0-7) or lo-correction (8-15)
    const int lg = lane >> 4;
    const int b0 = blockIdx.x * NB;
    const bool lo8 = (lr < 8);
    const int rb = lo8 ? 0 : 2;         // r-split: which 2 acc slots this lane activates

    // ---- stage x transposed ----
    {
        const float4* xs = (const float4*)(x + (size_t)b0 * TT);
        #pragma unroll
        for (int i = 0; i < 2; ++i) {
            int idx = i * NT + tid;
            float4 v = xs[idx];
            int b  = idx >> 7;
            int t4 = (idx & 127) << 2;
            x_lds2[t4 + 0][b] = v.x;
            x_lds2[t4 + 1][b] = v.y;
            x_lds2[t4 + 2][b] = v.z;
            x_lds2[t4 + 3][b] = v.w;
        }
    }
    // ---- zero h buffers (3072 ints total) ----
    {
        int* hz = (int*)h1ring;          // 2048 ints
        #pragma unroll
        for (int i = 0; i < 4; ++i) hz[i * NT + tid] = 0;
        int* h2z = (int*)h2buf;          // 1024 ints
        #pragma unroll
        for (int i = 0; i < 2; ++i) h2z[i * NT + tid] = 0;
    }
    if (tid == 0) { c0 = 0; c1c = 0; c1d = 0; }

    // ---- per-wave static weights (pre-scaled by -log2e / -2log2e per gate row) ----
    bf16x8 Ahi[16], Alo[16];
    float bias[16], wxv[16];
    float cst0 = 0.f, cst1 = 0.f;
    const int base_u = 16 * wloc + 4 * lg;
    const int u0 = base_u + rb;
    const int wo  = ((lr & 7) + 16 * (base_u >> 3)) * 8 + (base_u & 7) + rb;
    const int fro = lane * 8;

    if (!isL1) {
        #pragma unroll
        for (int j = 0; j < 4; ++j) {
            const float sj = (j == 2) ? (-2.0f * L2E) : (-L2E);
            const int row = j * 64 + 16 * wloc + lr;
            #pragma unroll
            for (int kt = 0; kt < 2; ++kt)
                split8s(W_hh0 + row * H + kt * 32 + 8 * lg, sj, Ahi[j * 2 + kt], Alo[j * 2 + kt]);
            const int rowc = j * 64 + base_u;
            #pragma unroll
            for (int r = 0; r < 4; ++r) {
                // masked: lanes lr>=8 accumulate corrections only -> no bias/x
                bias[j * 4 + r] = lo8 ? (b_ih0[rowc + r] + b_hh0[rowc + r]) * sj : 0.f;
                wxv[j * 4 + r]  = lo8 ? W_ih0[rowc + r] * sj : 0.f;
            }
        }
        #pragma unroll
        for (int i = 0; i < 8; ++i) { asm volatile("" : "+v"(Ahi[i])); asm volatile("" : "+v"(Alo[i])); }
        #pragma unroll
        for (int i = 0; i < 16; ++i) { asm volatile("" : "+v"(bias[i])); asm volatile("" : "+v"(wxv[i])); }
    } else {
        #pragma unroll
        for (int j = 0; j < 4; ++j) {
            const float sj = (j == 2) ? (-2.0f * L2E) : (-L2E);
            const int row = j * 64 + 16 * wloc + lr;
            #pragma unroll
            for (int kt = 0; kt < 4; ++kt) {
                const float* p = (kt < 2) ? (W_ih1 + row * H + kt * 32 + 8 * lg)
                                          : (W_hh1 + row * H + (kt - 2) * 32 + 8 * lg);
                split8s(p, sj, Ahi[j * 4 + kt], Alo[j * 4 + kt]);
            }
            const int rowc = j * 64 + base_u;
            #pragma unroll
            for (int r = 0; r < 4; ++r)
                bias[j * 4 + r] = lo8 ? (b_ih1[rowc + r] + b_hh1[rowc + r]) * sj : 0.f;
        }
        #pragma unroll
        for (int i = 0; i < 16; ++i) { asm volatile("" : "+v"(Ahi[i])); asm volatile("" : "+v"(Alo[i])); }
        #pragma unroll
        for (int i = 0; i < 16; ++i) { asm volatile("" : "+v"(bias[i])); }
    }

    __syncthreads();

    if (!isL1) {
        // ============ L0: computes h1(t). Ring gate = L1's MFMA-end (c1c) ============
        for (int t = 0; t < TT; ++t) {
            waitge(&c0, 4 * t);                              // peers done t-1
            if (t >= 4) waitge_sleep(&c1c, 4 * (t - 3));     // ring slot t&3 consumed
            const unsigned short* ph = &h1ring[(t - 1) & 3][0];
            bf16x8 Bh0 = *(const bf16x8*)(ph + fro);
            bf16x8 Bh1 = *(const bf16x8*)(ph + 512 + fro);
            const float xv = x_lds2[t][lane & 7];
            f32x4 acc[4];
            #pragma unroll
            for (int j = 0; j < 4; ++j)
                #pragma unroll
                for (int r = 0; r < 4; ++r)
                    acc[j][r] = fmaf(wxv[j * 4 + r], xv, bias[j * 4 + r]);
            __builtin_amdgcn_s_setprio(1);
            #pragma unroll
            for (int j = 0; j < 4; ++j) {
                MFMA(Ahi[j * 2 + 0], Bh0, acc[j]);
                MFMA(Alo[j * 2 + 0], Bh0, acc[j]);
                MFMA(Ahi[j * 2 + 1], Bh1, acc[j]);
                MFMA(Alo[j * 2 + 1], Bh1, acc[j]);
            }
            __builtin_amdgcn_s_setprio(0);
            // fold cols c/c+8 (main/corr) and r-split select
            float zs[4][2];
            #pragma unroll
            for (int j = 0; j < 4; ++j) {
                const float s0 = acc[j][0] + xor8(acc[j][0]);
                const float s1 = acc[j][1] + xor8(acc[j][1]);
                const float s2 = acc[j][2] + xor8(acc[j][2]);
                const float s3 = acc[j][3] + xor8(acc[j][3]);
                zs[j][0] = lo8 ? s0 : s2;
                zs[j][1] = lo8 ? s1 : s3;
            }
            cst0 = fmaf(sigm_pre(zs[1][0]), cst0, sigm_pre(zs[0][0]) * tanh_pre(zs[2][0]));
            cst1 = fmaf(sigm_pre(zs[1][1]), cst1, sigm_pre(zs[0][1]) * tanh_pre(zs[2][1]));
            const float hv0 = sigm_pre(zs[3][0]) * tanh_fast(cst0);
            const float hv1 = sigm_pre(zs[3][1]) * tanh_fast(cst1);
            unsigned p, q;
            asm("v_cvt_pk_bf16_f32 %0, %1, %2" : "=v"(p) : "v"(hv0), "v"(hv1));
            const float r0 = hv0 - __uint_as_float(p << 16);
            const float r1 = hv1 - __uint_as_float(p & 0xffff0000u);
            asm("v_cvt_pk_bf16_f32 %0, %1, %2" : "=v"(q) : "v"(r0), "v"(r1));
            *(unsigned*)&h1ring[t & 3][wo]      = p;    // hi -> col c
            *(unsigned*)&h1ring[t & 3][wo + 64] = q;    // lo -> col c+8
            signal(&c0);
        }
    } else {
        // ============ L1: iter t computes h2(t-1) ============
        for (int t = 1; t <= TT; ++t) {
            waitge(&c1d, 4 * (t - 1));                // peers' h2(t-2) written
            waitge(&c0, 4 * t);                       // h1(t-1) ready (rarely binds)
            const unsigned short* p1 = &h1ring[(t - 1) & 3][0];
            const unsigned short* p2 = &h2buf[(t - 2) & 1][0];
            bf16x8 Bh[4];
            Bh[0] = *(const bf16x8*)(p1 + fro);
            Bh[1] = *(const bf16x8*)(p1 + 512 + fro);
            Bh[2] = *(const bf16x8*)(p2 + fro);
            Bh[3] = *(const bf16x8*)(p2 + 512 + fro);
            f32x4 acc[4];
            #pragma unroll
            for (int j = 0; j < 4; ++j)
                #pragma unroll
                for (int r = 0; r < 4; ++r)
                    acc[j][r] = bias[j * 4 + r];
            __builtin_amdgcn_s_setprio(1);
            #pragma unroll
            for (int j = 0; j < 4; ++j)
                #pragma unroll
                for (int kt = 0; kt < 4; ++kt) {
                    MFMA(Ahi[j * 4 + kt], Bh[kt], acc[j]);
                    MFMA(Alo[j * 4 + kt], Bh[kt], acc[j]);
                }
            __builtin_amdgcn_s_setprio(0);
            // early ring-consume signal: releases L0 at our MFMA-end -> anti-phase
            __builtin_amdgcn_sched_barrier(0);
            signal(&c1c);
            float zs[4][2];
            #pragma unroll
            for (int j = 0; j < 4; ++j) {
                const float s0 = acc[j][0] + xor8(acc[j][0]);
                const float s1 = acc[j][1] + xor8(acc[j][1]);
                const float s2 = acc[j][2] + xor8(acc[j][2]);
                const float s3 = acc[j][3] + xor8(acc[j][3]);
                zs[j][0] = lo8 ? s0 : s2;
                zs[j][1] = lo8 ? s1 : s3;
            }
            cst0 = fmaf(sigm_pre(zs[1][0]), cst0, sigm_pre(zs[0][0]) * tanh_pre(zs[2][0]));
            cst1 = fmaf(sigm_pre(zs[1][1]), cst1, sigm_pre(zs[0][1]) * tanh_pre(zs[2][1]));
            const float hv0 = sigm_pre(zs[3][0]) * tanh_fast(cst0);
            const float hv1 = sigm_pre(zs[3][1]) * tanh_fast(cst1);
            unsigned p, q;
            asm("v_cvt_pk_bf16_f32 %0, %1, %2" : "=v"(p) : "v"(hv0), "v"(hv1));
            const float r0 = hv0 - __uint_as_float(p << 16);
            const float r1 = hv1 - __uint_as_float(p & 0xffff0000u);
            asm("v_cvt_pk_bf16_f32 %0, %1, %2" : "=v"(q) : "v"(r0), "v"(r1));
            *(unsigned*)&h2buf[(t - 1) & 1][wo]      = p;
            *(unsigned*)&h2buf[(t - 1) & 1][wo + 64] = q;
            if (t == TT) {
                const float s = fc_W[u0] * hv0 + fc_W[u0 + 1] * hv1;
                fc_part[(wid - 4) * 8 + lg * 2 + (lo8 ? 0 : 1)][lr & 7] = s;
            }
            signal(&c1d);
        }
    }

    __syncthreads();

    // ---- final FC reduce (deterministic) ----
    if (tid < NB) {
        float s = fc_b[0];
        #pragma unroll
        for (int i = 0; i < 32; ++i) s += fc_part[i][tid];
        out[b0 + tid] = s;
    }
}

} // namespace

extern "C" void kernel_launch(void* const* d_in, const int* in_sizes, int n_in,
                              void* d_out, int out_size, void* d_ws, size_t ws_size,
                              hipStream_t stream)
{
    const float* x     = (const float*)d_in[0];
    const float* W_ih0 = (const float*)d_in[1];
    const float* W_hh0 = (const float*)d_in[2];
    const float* b_ih0 = (const float*)d_in[3];
    const float* b_hh0 = (const float*)d_in[4];
    const float* W_ih1 = (const float*)d_in[5];
    const float* W_hh1 = (const float*)d_in[6];
    const float* b_ih1 = (const float*)d_in[7];
    const float* b_hh1 = (const float*)d_in[8];
    const float* fc_W  = (const float*)d_in[9];
    const float* fc_b  = (const float*)d_in[10];
    float* out = (float*)d_out;

    const int B = in_sizes[0] / TT;          // 2048
    dim3 grid(B / NB), block(NT);            // 256 blocks x 512 threads
    hipLaunchKernelGGL(lstm2_mfma_kernel, grid, block, 0, stream,
                       x, W_ih0, W_hh0, b_ih0, b_hh0,
                       W_ih1, W_hh1, b_ih1, b_hh1, fc_W, fc_b, out);
}